// Round 13
// baseline (184.622 us; speedup 1.0000x reference)
//
#include <hip/hip_runtime.h>
#include <math.h>

#define L_SEQ 4096
#define D_HEAD 64
#define M_WIN 128
#define WIN 257              // 2*M+1
#define QB 16                // query rows per block (4 waves x 4 rows)
#define W 272                // WIN + QB - 1 = 17*16 exactly
#define WF4 68               // W/4
#define ATTS 272             // att row stride (floats); f4 stride 68
#define SCALE 0.125f         // 1/sqrt(64)

// wave-uniform lane read via VALU (v_readlane -> SGPR), not LDS pipe
#define RL(v, i) __uint_as_float(__builtin_amdgcn_readlane(__float_as_uint(v), (i)))

static __device__ __forceinline__ unsigned bfr(float x) {      // f32->bf16 RNE
    unsigned u = __float_as_uint(x);
    return (u + 0x7fffu + ((u >> 16) & 1u)) >> 16;
}
static __device__ __forceinline__ unsigned bfpack(float lo, float hi) {
    return bfr(lo) | (bfr(hi) << 16);
}

// K tile: [272 rows][8 uint4 slots], slot = c8 ^ (row&7); one uint4 = 8 bf16.
// Phase-B reads (lane owns col, fixed c8): slot varies over all 8 values per
// 8 consecutive cols -> uniform bank load, conflict-free. Staging writes:
// 8 threads per row hit 8 distinct slots.
__global__ __launch_bounds__(256, 3) void win_attn_kernel(
    const float* __restrict__ Q, const float* __restrict__ K,
    const float* __restrict__ V, float* __restrict__ OutO,
    float* __restrict__ OutA)
{
    extern __shared__ float smem[];
    uint4* k_su = (uint4*)smem;              // [272][8] uint4 = 34816 B
    float* att  = smem + 2176 * 4;           // [QB][ATTS] = 17408 B

    const int t  = threadIdx.x;
    const int w  = t >> 6;                   // wave 0..3 -> q rows 4w..4w+3
    const int ln = t & 63;

    // XCD-bijective swizzle: 2048 blocks, 8 XCDs, 256 contiguous tiles each.
    const int bid = (blockIdx.x & 7) * 256 + (blockIdx.x >> 3);
    const int b   = bid >> 8;
    const int q0  = (bid & 255) * QB;

    int s0 = q0 - M_WIN;
    if (s0 < 0) s0 = 0;
    if (s0 > L_SEQ - WIN) s0 = L_SEQ - WIN;
    const int wcount = (L_SEQ - s0 < W) ? (L_SEQ - s0) : W;

    // ---------------- Phase A: stage K (bf16, swizzled); q rows -> registers
    {
        const float4* Kg = (const float4*)(K + ((size_t)(b * L_SEQ + s0)) * D_HEAD);
        #pragma unroll 3
        for (int idx = t; idx < W * 8; idx += 256) {
            int row = idx >> 3, c8 = idx & 7;
            int gr  = (row < wcount) ? row : wcount - 1;
            float4 a  = Kg[(size_t)gr * 16 + c8 * 2];
            float4 bb = Kg[(size_t)gr * 16 + c8 * 2 + 1];
            uint4 d;
            d.x = bfpack(a.x, a.y);   d.y = bfpack(a.z, a.w);
            d.z = bfpack(bb.x, bb.y); d.w = bfpack(bb.z, bb.w);
            k_su[row * 8 + (c8 ^ (row & 7))] = d;
        }
    }
    const int r0g = q0 + 4 * w;              // this wave's four global q rows
    float qv0 = Q[((size_t)(b * L_SEQ) + r0g)     * D_HEAD + ln];
    float qv1 = Q[((size_t)(b * L_SEQ) + r0g + 1) * D_HEAD + ln];
    float qv2 = Q[((size_t)(b * L_SEQ) + r0g + 2) * D_HEAD + ln];
    float qv3 = Q[((size_t)(b * L_SEQ) + r0g + 3) * D_HEAD + ln];
    __syncthreads();                         // the ONLY block-wide barrier

    // ---------------- Phase B: scores; lane owns cols cg*64+ln --------------
    float p0[5], p1[5], p2[5], p3[5];
    {
        const uint4* kp[5];
        int msk[5];
        #pragma unroll
        for (int cg = 0; cg < 5; ++cg) {
            int colr = cg * 64 + ln;
            int col  = (colr < W) ? colr : W - 1;   // clamped for memory
            kp[cg]  = k_su + (size_t)col * 8;
            msk[cg] = col & 7;
            p0[cg] = 0.f; p1[cg] = 0.f; p2[cg] = 0.f; p3[cg] = 0.f;
        }
        #pragma unroll
        for (int c8 = 0; c8 < 8; ++c8) {
            float a0 = RL(qv0, 8*c8+0), a1 = RL(qv0, 8*c8+1),
                  a2 = RL(qv0, 8*c8+2), a3 = RL(qv0, 8*c8+3),
                  a4 = RL(qv0, 8*c8+4), a5 = RL(qv0, 8*c8+5),
                  a6 = RL(qv0, 8*c8+6), a7 = RL(qv0, 8*c8+7);
            float b0 = RL(qv1, 8*c8+0), b1 = RL(qv1, 8*c8+1),
                  b2 = RL(qv1, 8*c8+2), b3 = RL(qv1, 8*c8+3),
                  b4 = RL(qv1, 8*c8+4), b5 = RL(qv1, 8*c8+5),
                  b6 = RL(qv1, 8*c8+6), b7 = RL(qv1, 8*c8+7);
            float c0 = RL(qv2, 8*c8+0), c1 = RL(qv2, 8*c8+1),
                  c2 = RL(qv2, 8*c8+2), c3 = RL(qv2, 8*c8+3),
                  c4 = RL(qv2, 8*c8+4), c5 = RL(qv2, 8*c8+5),
                  c6 = RL(qv2, 8*c8+6), c7 = RL(qv2, 8*c8+7);
            float d0 = RL(qv3, 8*c8+0), d1 = RL(qv3, 8*c8+1),
                  d2 = RL(qv3, 8*c8+2), d3 = RL(qv3, 8*c8+3),
                  d4 = RL(qv3, 8*c8+4), d5 = RL(qv3, 8*c8+5),
                  d6 = RL(qv3, 8*c8+6), d7 = RL(qv3, 8*c8+7);
            #pragma unroll
            for (int cg = 0; cg < 5; ++cg) {
                uint4 kk = kp[cg][c8 ^ msk[cg]];
                float e0 = __uint_as_float(kk.x << 16);
                float e1 = __uint_as_float(kk.x & 0xffff0000u);
                float e2 = __uint_as_float(kk.y << 16);
                float e3 = __uint_as_float(kk.y & 0xffff0000u);
                float e4 = __uint_as_float(kk.z << 16);
                float e5 = __uint_as_float(kk.z & 0xffff0000u);
                float e6 = __uint_as_float(kk.w << 16);
                float e7 = __uint_as_float(kk.w & 0xffff0000u);
                p0[cg] += a0*e0 + a1*e1 + a2*e2 + a3*e3
                        + a4*e4 + a5*e5 + a6*e6 + a7*e7;
                p1[cg] += b0*e0 + b1*e1 + b2*e2 + b3*e3
                        + b4*e4 + b5*e5 + b6*e6 + b7*e7;
                p2[cg] += c0*e0 + c1*e1 + c2*e2 + c3*e3
                        + c4*e4 + c5*e5 + c6*e6 + c7*e7;
                p3[cg] += d0*e0 + d1*e1 + d2*e2 + d3*e3
                        + d4*e4 + d5*e5 + d6*e6 + d7*e7;
            }
        }
        #pragma unroll
        for (int cg = 0; cg < 5; ++cg) {
            p0[cg] *= SCALE; p1[cg] *= SCALE; p2[cg] *= SCALE; p3[cg] *= SCALE;
        }
    }

    // ---------------- Phase C: in-register masked softmax, 4 rows/wave ------
    {
        int lo[4];
        #pragma unroll
        for (int r = 0; r < 4; ++r) {
            int st = r0g + r - M_WIN;
            if (st < 0) st = 0;
            if (st > L_SEQ - WIN) st = L_SEQ - WIN;
            lo[r] = st - s0;
        }
        float m0 = -1e30f, m1 = -1e30f, m2 = -1e30f, m3 = -1e30f;
        #pragma unroll
        for (int cg = 0; cg < 5; ++cg) {
            int colr = cg * 64 + ln;
            p0[cg] = (colr >= lo[0] && colr < lo[0] + WIN) ? p0[cg] : -1e30f;
            p1[cg] = (colr >= lo[1] && colr < lo[1] + WIN) ? p1[cg] : -1e30f;
            p2[cg] = (colr >= lo[2] && colr < lo[2] + WIN) ? p2[cg] : -1e30f;
            p3[cg] = (colr >= lo[3] && colr < lo[3] + WIN) ? p3[cg] : -1e30f;
            m0 = fmaxf(m0, p0[cg]); m1 = fmaxf(m1, p1[cg]);
            m2 = fmaxf(m2, p2[cg]); m3 = fmaxf(m3, p3[cg]);
        }
        #pragma unroll
        for (int off = 32; off >= 1; off >>= 1) {
            m0 = fmaxf(m0, __shfl_xor(m0, off));
            m1 = fmaxf(m1, __shfl_xor(m1, off));
            m2 = fmaxf(m2, __shfl_xor(m2, off));
            m3 = fmaxf(m3, __shfl_xor(m3, off));
        }
        float s0s = 0.f, s1s = 0.f, s2s = 0.f, s3s = 0.f;
        #pragma unroll
        for (int cg = 0; cg < 5; ++cg) {
            float e0 = (p0[cg] <= -1e29f) ? 0.f : __expf(p0[cg] - m0);
            float e1 = (p1[cg] <= -1e29f) ? 0.f : __expf(p1[cg] - m1);
            float e2 = (p2[cg] <= -1e29f) ? 0.f : __expf(p2[cg] - m2);
            float e3 = (p3[cg] <= -1e29f) ? 0.f : __expf(p3[cg] - m3);
            p0[cg] = e0; p1[cg] = e1; p2[cg] = e2; p3[cg] = e3;
            s0s += e0; s1s += e1; s2s += e2; s3s += e3;
        }
        #pragma unroll
        for (int off = 32; off >= 1; off >>= 1) {
            s0s += __shfl_xor(s0s, off); s1s += __shfl_xor(s1s, off);
            s2s += __shfl_xor(s2s, off); s3s += __shfl_xor(s3s, off);
        }
        const float i0 = 1.f / s0s, i1 = 1.f / s1s, i2 = 1.f / s2s, i3 = 1.f / s3s;
        #pragma unroll
        for (int cg = 0; cg < 5; ++cg) {
            int colr = cg * 64 + ln;
            if (colr < W) {
                att[(4 * w)     * ATTS + colr] = p0[cg] * i0;  // 0 outside win
                att[(4 * w + 1) * ATTS + colr] = p1[cg] * i1;
                att[(4 * w + 2) * ATTS + colr] = p2[cg] * i2;
                att[(4 * w + 3) * ATTS + colr] = p3[cg] * i3;
            }
        }
    }
    // No barrier: everything below reads only this wave's own att rows.

    // ---------------- Phase E: PV; 4 rows/wave; V from global ---------------
    {
        const int cq = ln >> 4;              // which f4 of the 16-col group
        const int dg = ln & 15;              // d float4-group
        const float4* Vg4 = (const float4*)(V + ((size_t)(b * L_SEQ + s0)) * D_HEAD);
        const float4* a4r0 = (const float4*)(att + (4 * w)     * ATTS);
        const float4* a4r1 = (const float4*)(att + (4 * w + 1) * ATTS);
        const float4* a4r2 = (const float4*)(att + (4 * w + 2) * ATTS);
        const float4* a4r3 = (const float4*)(att + (4 * w + 3) * ATTS);
        float4 acc0 = {0.f,0.f,0.f,0.f}, acc1 = {0.f,0.f,0.f,0.f};
        float4 acc2 = {0.f,0.f,0.f,0.f}, acc3 = {0.f,0.f,0.f,0.f};
        #pragma unroll 1
        for (int G = 0; G < 17; ++G) {       // 17*16 = 272 cols exactly
            float4 pa = a4r0[4 * G + cq];
            float4 pb = a4r1[4 * G + cq];
            float4 pc = a4r2[4 * G + cq];
            float4 pd = a4r3[4 * G + cq];
            #pragma unroll
            for (int e = 0; e < 4; ++e) {
                int col  = 16 * G + 4 * cq + e;
                int colc = (col < wcount) ? col : wcount - 1;   // p is 0 there
                float4 vv = Vg4[(size_t)colc * 16 + dg];
                float fa = (e == 0) ? pa.x : (e == 1) ? pa.y : (e == 2) ? pa.z : pa.w;
                float fb = (e == 0) ? pb.x : (e == 1) ? pb.y : (e == 2) ? pb.z : pb.w;
                float fc = (e == 0) ? pc.x : (e == 1) ? pc.y : (e == 2) ? pc.z : pc.w;
                float fd = (e == 0) ? pd.x : (e == 1) ? pd.y : (e == 2) ? pd.z : pd.w;
                acc0.x += fa * vv.x; acc0.y += fa * vv.y;
                acc0.z += fa * vv.z; acc0.w += fa * vv.w;
                acc1.x += fb * vv.x; acc1.y += fb * vv.y;
                acc1.z += fb * vv.z; acc1.w += fb * vv.w;
                acc2.x += fc * vv.x; acc2.y += fc * vv.y;
                acc2.z += fc * vv.z; acc2.w += fc * vv.w;
                acc3.x += fd * vv.x; acc3.y += fd * vv.y;
                acc3.z += fd * vv.z; acc3.w += fd * vv.w;
            }
        }
        #pragma unroll
        for (int off = 16; off <= 32; off <<= 1) {
            acc0.x += __shfl_xor(acc0.x, off); acc0.y += __shfl_xor(acc0.y, off);
            acc0.z += __shfl_xor(acc0.z, off); acc0.w += __shfl_xor(acc0.w, off);
            acc1.x += __shfl_xor(acc1.x, off); acc1.y += __shfl_xor(acc1.y, off);
            acc1.z += __shfl_xor(acc1.z, off); acc1.w += __shfl_xor(acc1.w, off);
            acc2.x += __shfl_xor(acc2.x, off); acc2.y += __shfl_xor(acc2.y, off);
            acc2.z += __shfl_xor(acc2.z, off); acc2.w += __shfl_xor(acc2.w, off);
            acc3.x += __shfl_xor(acc3.x, off); acc3.y += __shfl_xor(acc3.y, off);
            acc3.z += __shfl_xor(acc3.z, off); acc3.w += __shfl_xor(acc3.w, off);
        }
        if (ln < 16) {
            float* ob = OutO + ((size_t)(b * L_SEQ + r0g)) * D_HEAD;
            ((float4*)ob)[dg]      = acc0;
            ((float4*)ob)[16 + dg] = acc1;
            ((float4*)ob)[32 + dg] = acc2;
            ((float4*)ob)[48 + dg] = acc3;
        }
    }

    // ---------------- Phase D: dense stream of this wave's 4 att rows -------
    if ((s0 & 3) == 0) {
        const int zlo = s0 >> 2;
        #pragma unroll
        for (int r = 0; r < 4; ++r) {
            float4* rowp = (float4*)(OutA + ((size_t)(b * L_SEQ + r0g + r)) * L_SEQ);
            const float4* arow = (const float4*)(att + (4 * w + r) * ATTS);
            #pragma unroll 4
            for (int j = 0; j < 16; ++j) {
                int f4i = j * 64 + ln;
                int u4  = f4i - zlo;
                float4 wv = {0.f,0.f,0.f,0.f};
                if (u4 >= 0 && u4 < WF4) wv = arow[u4];     // aligned b128 read
                rowp[f4i] = wv;                             // 1 KB/instr, clean
            }
        }
    } else {   // rare top-edge blocks (s0 = 3839)
        #pragma unroll
        for (int r = 0; r < 4; ++r) {
            float4* rowp = (float4*)(OutA + ((size_t)(b * L_SEQ + r0g + r)) * L_SEQ);
            const float* arow = att + (4 * w + r) * ATTS;
            #pragma unroll 2
            for (int j = 0; j < 16; ++j) {
                int f4i = j * 64 + ln;
                int u   = 4 * f4i - s0;
                float4 wv;
                wv.x = (u     >= 0 && u     < W) ? arow[u]     : 0.f;
                wv.y = (u + 1 >= 0 && u + 1 < W) ? arow[u + 1] : 0.f;
                wv.z = (u + 2 >= 0 && u + 2 < W) ? arow[u + 2] : 0.f;
                wv.w = (u + 3 >= 0 && u + 3 < W) ? arow[u + 3] : 0.f;
                rowp[f4i] = wv;
            }
        }
    }
}

extern "C" void kernel_launch(void* const* d_in, const int* in_sizes, int n_in,
                              void* d_out, int out_size, void* d_ws, size_t ws_size,
                              hipStream_t stream) {
    const float* Q = (const float*)d_in[0];
    const float* K = (const float*)d_in[1];
    const float* V = (const float*)d_in[2];
    float* OutO = (float*)d_out;
    float* OutA = OutO + (size_t)8 * L_SEQ * D_HEAD;

    const int smem_bytes = 2176 * 16 + QB * ATTS * 4;   // 52224 B
    hipFuncSetAttribute((const void*)win_attn_kernel,
                        hipFuncAttributeMaxDynamicSharedMemorySize, smem_bytes);

    dim3 grid(8 * (L_SEQ / QB));    // 2048 blocks
    dim3 block(256);
    win_attn_kernel<<<grid, block, smem_bytes, stream>>>(Q, K, V, OutO, OutA);
}

// Round 14
// 168.309 us; speedup vs baseline: 1.0969x; 1.0969x over previous
//
#include <hip/hip_runtime.h>
#include <math.h>

#define L_SEQ 4096
#define D_HEAD 64
#define M_WIN 128
#define WIN 257              // 2*M+1
#define QB 8                 // query rows per block
#define W 264                // WIN + QB - 1
#define WF4 66               // W/4
#define ATTS 272             // padded att row stride (floats); f4 stride 68
#define SCALE 0.125f         // 1/sqrt(64)

// wave-uniform lane read via VALU (v_readlane -> SGPR), not LDS pipe
#define RL(v, i) __uint_as_float(__builtin_amdgcn_readlane(__float_as_uint(v), (i)))

static __device__ __forceinline__ unsigned bfr(float x) {      // f32->bf16 RNE
    unsigned u = __float_as_uint(x);
    return (u + 0x7fffu + ((u >> 16) & 1u)) >> 16;
}
static __device__ __forceinline__ unsigned bfpack(float lo, float hi) {
    return bfr(lo) | (bfr(hi) << 16);
}

// K tile: [264 rows][8 uint4 slots], slot = c8 ^ (row&7); one uint4 = 8 bf16.
// Phase-B reads (lane owns col, fixed c8): slot varies over all 8 values per
// 8 consecutive cols -> uniform bank load (no conflict). Staging writes:
// 8 threads per row hit 8 distinct slots.
__global__ __launch_bounds__(256, 3) void win_attn_kernel(
    const float* __restrict__ Q, const float* __restrict__ K,
    const float* __restrict__ V, float* __restrict__ OutO,
    float* __restrict__ OutA)
{
    extern __shared__ float smem[];
    uint4* k_su = (uint4*)smem;              // [264][8] uint4 = 33792 B
    float* att  = smem + 2112 * 4;           // [QB][ATTS] = 8704 B

    const int t  = threadIdx.x;
    const int w  = t >> 6;                   // wave 0..3 -> q rows {2w, 2w+1}
    const int ln = t & 63;

    // NATIVE mapping (round-1 evidence: FETCH=71MB; the XCD remap measured
    // 528-602MB in rounds 6/7 — HW workgroup->XCD assignment is undefined,
    // so hand-remapping can scatter co-resident windows past L2 capacity).
    const int bid = blockIdx.x;
    const int b   = bid >> 9;
    const int q0  = (bid & 511) * QB;

    int s0 = q0 - M_WIN;
    if (s0 < 0) s0 = 0;
    if (s0 > L_SEQ - WIN) s0 = L_SEQ - WIN;
    const int wcount = (L_SEQ - s0 < W) ? (L_SEQ - s0) : W;

    // ---------------- Phase A: stage K (bf16, swizzled); q rows -> registers
    {
        const float4* Kg = (const float4*)(K + ((size_t)(b * L_SEQ + s0)) * D_HEAD);
        #pragma unroll 3
        for (int idx = t; idx < 264 * 8; idx += 256) {
            int row = idx >> 3, c8 = idx & 7;
            int gr  = (row < wcount) ? row : wcount - 1;
            float4 a  = Kg[(size_t)gr * 16 + c8 * 2];
            float4 bb = Kg[(size_t)gr * 16 + c8 * 2 + 1];
            uint4 d;
            d.x = bfpack(a.x, a.y);   d.y = bfpack(a.z, a.w);
            d.z = bfpack(bb.x, bb.y); d.w = bfpack(bb.z, bb.w);
            k_su[row * 8 + (c8 ^ (row & 7))] = d;
        }
    }
    const int r0g = q0 + 2 * w;              // this wave's two global q rows
    const float qv0 = Q[((size_t)(b * L_SEQ) + r0g)     * D_HEAD + ln];
    const float qv1 = Q[((size_t)(b * L_SEQ) + r0g + 1) * D_HEAD + ln];
    // zero the att row pad (cols 264..271) for vectorized phase E reads
    if (ln < 16) {
        int r = 2 * w + (ln >> 3);
        att[r * ATTS + 264 + (ln & 7)] = 0.f;
    }
    __syncthreads();                         // the ONLY block-wide barrier

    // ---------------- Phase B: scores; lane owns cols cg*64+ln --------------
    float p0[5], p1[5];
    {
        const uint4* kp[5];
        int msk[5];
        #pragma unroll
        for (int cg = 0; cg < 5; ++cg) {
            int colr = cg * 64 + ln;
            int col  = (colr < W) ? colr : W - 1;   // clamped for memory
            kp[cg]  = k_su + (size_t)col * 8;
            msk[cg] = col & 7;
            p0[cg] = 0.f; p1[cg] = 0.f;
        }
        #pragma unroll
        for (int c8 = 0; c8 < 8; ++c8) {
            // q[8c8 .. 8c8+7] for both rows, via v_readlane (VALU, no LDS pipe)
            float a0 = RL(qv0, 8*c8+0), a1 = RL(qv0, 8*c8+1),
                  a2 = RL(qv0, 8*c8+2), a3 = RL(qv0, 8*c8+3),
                  a4 = RL(qv0, 8*c8+4), a5 = RL(qv0, 8*c8+5),
                  a6 = RL(qv0, 8*c8+6), a7 = RL(qv0, 8*c8+7);
            float b0 = RL(qv1, 8*c8+0), b1 = RL(qv1, 8*c8+1),
                  b2 = RL(qv1, 8*c8+2), b3 = RL(qv1, 8*c8+3),
                  b4 = RL(qv1, 8*c8+4), b5 = RL(qv1, 8*c8+5),
                  b6 = RL(qv1, 8*c8+6), b7 = RL(qv1, 8*c8+7);
            #pragma unroll
            for (int cg = 0; cg < 5; ++cg) {
                uint4 kk = kp[cg][c8 ^ msk[cg]];
                float e0 = __uint_as_float(kk.x << 16);
                float e1 = __uint_as_float(kk.x & 0xffff0000u);
                float e2 = __uint_as_float(kk.y << 16);
                float e3 = __uint_as_float(kk.y & 0xffff0000u);
                float e4 = __uint_as_float(kk.z << 16);
                float e5 = __uint_as_float(kk.z & 0xffff0000u);
                float e6 = __uint_as_float(kk.w << 16);
                float e7 = __uint_as_float(kk.w & 0xffff0000u);
                p0[cg] += a0*e0 + a1*e1 + a2*e2 + a3*e3
                        + a4*e4 + a5*e5 + a6*e6 + a7*e7;
                p1[cg] += b0*e0 + b1*e1 + b2*e2 + b3*e3
                        + b4*e4 + b5*e5 + b6*e6 + b7*e7;
            }
        }
        #pragma unroll
        for (int cg = 0; cg < 5; ++cg) { p0[cg] *= SCALE; p1[cg] *= SCALE; }
    }

    // ---------------- Phase C: in-register masked softmax (per wave) --------
    {
        int st0 = r0g - M_WIN;
        if (st0 < 0) st0 = 0;
        if (st0 > L_SEQ - WIN) st0 = L_SEQ - WIN;
        const int lo0 = st0 - s0;
        int st1 = r0g + 1 - M_WIN;
        if (st1 < 0) st1 = 0;
        if (st1 > L_SEQ - WIN) st1 = L_SEQ - WIN;
        const int lo1 = st1 - s0;

        float m0 = -1e30f, m1 = -1e30f;
        #pragma unroll
        for (int cg = 0; cg < 5; ++cg) {
            int colr = cg * 64 + ln;
            bool in0 = (colr >= lo0) && (colr < lo0 + WIN);
            bool in1 = (colr >= lo1) && (colr < lo1 + WIN);
            p0[cg] = in0 ? p0[cg] : -1e30f;
            p1[cg] = in1 ? p1[cg] : -1e30f;
            m0 = fmaxf(m0, p0[cg]);
            m1 = fmaxf(m1, p1[cg]);
        }
        #pragma unroll
        for (int off = 32; off >= 1; off >>= 1) {
            m0 = fmaxf(m0, __shfl_xor(m0, off));
            m1 = fmaxf(m1, __shfl_xor(m1, off));
        }
        float sum0 = 0.f, sum1 = 0.f;
        #pragma unroll
        for (int cg = 0; cg < 5; ++cg) {
            float e0 = (p0[cg] <= -1e29f) ? 0.f : __expf(p0[cg] - m0);
            float e1 = (p1[cg] <= -1e29f) ? 0.f : __expf(p1[cg] - m1);
            p0[cg] = e0; p1[cg] = e1;
            sum0 += e0; sum1 += e1;
        }
        #pragma unroll
        for (int off = 32; off >= 1; off >>= 1) {
            sum0 += __shfl_xor(sum0, off);
            sum1 += __shfl_xor(sum1, off);
        }
        const float inv0 = 1.f / sum0, inv1 = 1.f / sum1;
        #pragma unroll
        for (int cg = 0; cg < 5; ++cg) {
            int colr = cg * 64 + ln;
            if (colr < W) {
                att[(2 * w)     * ATTS + colr] = p0[cg] * inv0;  // 0 outside win
                att[(2 * w + 1) * ATTS + colr] = p1[cg] * inv1;
            }
        }
    }
    // No barrier: everything below reads only this wave's own att rows.

    // ---------------- Phase E: PV; vectorized att reads (b128 per 4 cols) ---
    {
        const int cq = ln >> 4;              // which f4 of the 16-col group
        const int dg = ln & 15;              // d float4-group
        const float4* Vg4 = (const float4*)(V + ((size_t)(b * L_SEQ + s0)) * D_HEAD);
        const float4* a4r0 = (const float4*)(att + (2 * w) * ATTS);
        const float4* a4r1 = (const float4*)(att + (2 * w + 1) * ATTS);
        float4 acc0 = {0.f,0.f,0.f,0.f}, acc1 = {0.f,0.f,0.f,0.f};
        #pragma unroll 2
        for (int G = 0; G < 17; ++G) {       // 17*16 = 272 cols (pad p = 0)
            float4 pa = a4r0[4 * G + cq];
            float4 pb = a4r1[4 * G + cq];
            #pragma unroll
            for (int e = 0; e < 4; ++e) {
                int col  = 16 * G + 4 * cq + e;
                int colc = (col < wcount) ? col : wcount - 1;   // p is 0 there
                float4 vv = Vg4[(size_t)colc * 16 + dg];
                float fa = (e == 0) ? pa.x : (e == 1) ? pa.y : (e == 2) ? pa.z : pa.w;
                float fb = (e == 0) ? pb.x : (e == 1) ? pb.y : (e == 2) ? pb.z : pb.w;
                acc0.x += fa * vv.x; acc0.y += fa * vv.y;
                acc0.z += fa * vv.z; acc0.w += fa * vv.w;
                acc1.x += fb * vv.x; acc1.y += fb * vv.y;
                acc1.z += fb * vv.z; acc1.w += fb * vv.w;
            }
        }
        #pragma unroll
        for (int off = 16; off <= 32; off <<= 1) {
            acc0.x += __shfl_xor(acc0.x, off); acc0.y += __shfl_xor(acc0.y, off);
            acc0.z += __shfl_xor(acc0.z, off); acc0.w += __shfl_xor(acc0.w, off);
            acc1.x += __shfl_xor(acc1.x, off); acc1.y += __shfl_xor(acc1.y, off);
            acc1.z += __shfl_xor(acc1.z, off); acc1.w += __shfl_xor(acc1.w, off);
        }
        if (ln < 16) {
            float4* o4 = (float4*)(OutO + ((size_t)(b * L_SEQ + r0g)) * D_HEAD);
            o4[dg]      = acc0;
            o4[16 + dg] = acc1;
        }
    }

    // ---------------- Phase D: dense stream of this wave's 2 att rows -------
    if ((s0 & 3) == 0) {
        const int zlo = s0 >> 2;
        #pragma unroll
        for (int r = 0; r < 2; ++r) {
            float4* rowp = (float4*)(OutA + ((size_t)(b * L_SEQ + r0g + r)) * L_SEQ);
            const float4* arow = (const float4*)(att + (2 * w + r) * ATTS);
            #pragma unroll 4
            for (int j = 0; j < 16; ++j) {
                int f4i = j * 64 + ln;
                int u4  = f4i - zlo;
                float4 wv = {0.f,0.f,0.f,0.f};
                if (u4 >= 0 && u4 < WF4) wv = arow[u4];     // aligned b128 read
                rowp[f4i] = wv;                             // 1 KB/instr, clean
            }
        }
    } else {   // rare top-edge blocks (s0 = 3839)
        #pragma unroll
        for (int r = 0; r < 2; ++r) {
            float4* rowp = (float4*)(OutA + ((size_t)(b * L_SEQ + r0g + r)) * L_SEQ);
            const float* arow = att + (2 * w + r) * ATTS;
            #pragma unroll 2
            for (int j = 0; j < 16; ++j) {
                int f4i = j * 64 + ln;
                int u   = 4 * f4i - s0;
                float4 wv;
                wv.x = (u     >= 0 && u     < W) ? arow[u]     : 0.f;
                wv.y = (u + 1 >= 0 && u + 1 < W) ? arow[u + 1] : 0.f;
                wv.z = (u + 2 >= 0 && u + 2 < W) ? arow[u + 2] : 0.f;
                wv.w = (u + 3 >= 0 && u + 3 < W) ? arow[u + 3] : 0.f;
                rowp[f4i] = wv;
            }
        }
    }
}

extern "C" void kernel_launch(void* const* d_in, const int* in_sizes, int n_in,
                              void* d_out, int out_size, void* d_ws, size_t ws_size,
                              hipStream_t stream) {
    const float* Q = (const float*)d_in[0];
    const float* K = (const float*)d_in[1];
    const float* V = (const float*)d_in[2];
    float* OutO = (float*)d_out;
    float* OutA = OutO + (size_t)8 * L_SEQ * D_HEAD;

    const int smem_bytes = 2112 * 16 + QB * ATTS * 4;   // 42496 B
    hipFuncSetAttribute((const void*)win_attn_kernel,
                        hipFuncAttributeMaxDynamicSharedMemorySize, smem_bytes);

    dim3 grid(8 * (L_SEQ / QB));    // 4096 blocks
    dim3 block(256);
    win_attn_kernel<<<grid, block, smem_bytes, stream>>>(Q, K, V, OutO, OutA);
}